// Round 4
// baseline (239.420 us; speedup 1.0000x reference)
//
#include <hip/hip_runtime.h>
#include <stdint.h>

#define NTOT 8192
#define BHALF 4096
#define DZ 512
#define DC 128
#define CS 8
#define TEMPV 0.5f
#define FIXM 16.0f

typedef __attribute__((ext_vector_type(8))) short short8;     // 8 bf16 (4 VGPRs)
typedef __attribute__((ext_vector_type(8))) unsigned short u16x8;
typedef __attribute__((ext_vector_type(4))) float f32x4;
typedef __attribute__((ext_vector_type(4))) float floatx4;
typedef unsigned short u16;

__device__ __forceinline__ u16 f2bf(float x) {
  uint32_t u = __builtin_bit_cast(uint32_t, x);
  u += 0x7fffu + ((u >> 16) & 1u);   // RNE
  return (u16)(u >> 16);
}

#define MFMA16(a, b, c) __builtin_amdgcn_mfma_f32_16x16x32_bf16((a), (b), (c), 0, 0, 0)

// ---------------- convert: fp32 -> bf16 in MFMA-frag-tiled layout ----------------
// Tiled layout: 16B chunk index ((ct*KCH + kk)*64 + lane), lane=(lq,ln), holds
// x[ct*16+ln][kk*32+lq*8 .. +7]. This is simultaneously the A-frag layout for
// row-tile ct and the B-frag layout for col-tile ct -> all fused-kernel loads
// are global_load_dwordx4 at base+lane*16 (perfectly coalesced, no LDS needed).
__global__ void convert_kernel(const float* __restrict__ z_i, const float* __restrict__ z_j,
                               const float* __restrict__ c_i, const float* __restrict__ c_j,
                               u16* __restrict__ zbT, u16* __restrict__ cbT) {
  const int ZCH = NTOT * DZ / 8;   // 524288 16B chunks
  const int CCH = NTOT * DC / 8;   // 131072
  int i = blockIdx.x * blockDim.x + threadIdx.x;
  if (i >= ZCH + CCH) return;
  if (i < ZCH) {
    int lane6 = i & 63;
    int f = i >> 6;                 // ct*16 + kk
    int ct = f >> 4, kk = f & 15;
    int ln = lane6 & 15, lq = lane6 >> 4;
    int row = ct * 16 + ln;
    int k = kk * 32 + lq * 8;
    const float* src = (row < BHALF) ? (z_i + (size_t)row * DZ + k)
                                     : (z_j + (size_t)(row - BHALF) * DZ + k);
    floatx4 v0 = *(const floatx4*)src;
    floatx4 v1 = *(const floatx4*)(src + 4);
    u16x8 o;
    o[0]=f2bf(v0[0]); o[1]=f2bf(v0[1]); o[2]=f2bf(v0[2]); o[3]=f2bf(v0[3]);
    o[4]=f2bf(v1[0]); o[5]=f2bf(v1[1]); o[6]=f2bf(v1[2]); o[7]=f2bf(v1[3]);
    *(u16x8*)(zbT + (size_t)i * 8) = o;
  } else {
    int i2 = i - ZCH;
    int lane6 = i2 & 63;
    int f = i2 >> 6;                // ct*4 + kk
    int ct = f >> 2, kk = f & 3;
    int ln = lane6 & 15, lq = lane6 >> 4;
    int row = ct * 16 + ln;
    int k = kk * 32 + lq * 8;
    const float* src = (row < BHALF) ? (c_i + (size_t)row * DC + k)
                                     : (c_j + (size_t)(row - BHALF) * DC + k);
    floatx4 v0 = *(const floatx4*)src;
    floatx4 v1 = *(const floatx4*)(src + 4);
    u16x8 o;
    o[0]=f2bf(v0[0]); o[1]=f2bf(v0[1]); o[2]=f2bf(v0[2]); o[3]=f2bf(v0[3]);
    o[4]=f2bf(v1[0]); o[5]=f2bf(v1[1]); o[6]=f2bf(v1[2]); o[7]=f2bf(v1[3]);
    *(u16x8*)(cbT + (size_t)i2 * 8) = o;
  }
}

// ---------------- fused flash-style lse kernel: no LDS, no barriers ----------------
// Block = 4 waves x 32 rows = 128 rows; cs = blk&7 -> one col stripe (64 col-tiles)
// per XCD (L2-resident; 8 waves/CU share the same B-frag stream -> L1 reuse).
// Fixed-M online sum: l += exp(s - 16); pair/diag entries excluded via
// wave-uniform correction blocks (recompute generic term -> exact cancellation).
__launch_bounds__(256, 2)
__global__ void fused_kernel(const u16* __restrict__ zbT, const u16* __restrict__ cbT,
                             float* __restrict__ sum_part, float* __restrict__ posArr) {
  const int tid  = threadIdx.x;
  const int w    = tid >> 6;
  const int lane = tid & 63;
  const int lq   = lane >> 4;
  const int ln   = lane & 15;

  const int cs = blockIdx.x & 7;
  const int rb = blockIdx.x >> 3;
  const int row_w = rb * 128 + w * 32;      // wave's 32 rows (2 sets of 16)
  const int rt0   = row_w >> 4;             // row-tile of set 0

  // A fragments (from tiled layout; chunk stride 64*8 u16 = 512)
  short8 a_z0[16], a_z1[16], a_c0[4], a_c1[4];
  {
    const u16* p0 = zbT + ((size_t)(rt0 * 16) * 64 + lane) * 8;
    const u16* p1 = zbT + ((size_t)((rt0 + 1) * 16) * 64 + lane) * 8;
#pragma unroll
    for (int kk = 0; kk < 16; ++kk) {
      a_z0[kk] = *(const short8*)(p0 + kk * 512);
      a_z1[kk] = *(const short8*)(p1 + kk * 512);
    }
    const u16* q0 = cbT + ((size_t)(rt0 * 4) * 64 + lane) * 8;
    const u16* q1 = cbT + ((size_t)((rt0 + 1) * 4) * 64 + lane) * 8;
#pragma unroll
    for (int kk = 0; kk < 4; ++kk) {
      a_c0[kk] = *(const short8*)(q0 + kk * 512);
      a_c1[kk] = *(const short8*)(q1 + kk * 512);
    }
  }

  float l_[8];
#pragma unroll
  for (int r = 0; r < 8; ++r) l_[r] = 0.0f;

  const int pct0 = (row_w ^ BHALF) >> 4;   // pair col-tile for set0 (set1: +1)
  const int dct0 = rt0;                    // diag col-tile for set0 (set1: +1)

  for (int it = 0; it < 64; ++it) {
    const int ct = cs * 64 + it;

    f32x4 ac0 = {0.f,0.f,0.f,0.f}, ac1 = {0.f,0.f,0.f,0.f};
#pragma unroll
    for (int kk = 0; kk < 4; ++kk) {
      const short8 b = *(const short8*)(cbT + ((size_t)(ct * 4 + kk) * 64 + lane) * 8);
      ac0 = MFMA16(a_c0[kk], b, ac0);
      ac1 = MFMA16(a_c1[kk], b, ac1);
    }
    f32x4 az0 = {0.f,0.f,0.f,0.f}, az1 = {0.f,0.f,0.f,0.f};
#pragma unroll
    for (int kk = 0; kk < 16; ++kk) {
      const short8 b = *(const short8*)(zbT + ((size_t)(ct * 16 + kk) * 64 + lane) * 8);
      az0 = MFMA16(a_z0[kk], b, az0);
      az1 = MFMA16(a_z1[kk], b, az1);
    }

    // generic epilogue: l += exp(s - M), s = zdot / max(cdot, 0.5)
#pragma unroll
    for (int r = 0; r < 4; ++r) {
      float tv0 = fmaxf(ac0[r], TEMPV);
      float sv0 = az0[r] * __builtin_amdgcn_rcpf(tv0);
      l_[r] += __expf(sv0 - FIXM);
      float tv1 = fmaxf(ac1[r], TEMPV);
      float sv1 = az1[r] * __builtin_amdgcn_rcpf(tv1);
      l_[4 + r] += __expf(sv1 - FIXM);
    }

    // corrections (wave-uniform branches; hit 2+2 of the 64 iterations)
#pragma unroll
    for (int s = 0; s < 2; ++s) {
      const f32x4 az = s ? az1 : az0;
      const f32x4 ac = s ? ac1 : ac0;
      if (ct == pct0 + s) {        // pair column tile for set s
#pragma unroll
        for (int r = 0; r < 4; ++r) {
          if (ln == lq * 4 + r) {  // the pair lane for this row
            float tv = fmaxf(ac[r], TEMPV);
            float sv = az[r] * __builtin_amdgcn_rcpf(tv);
            l_[s * 4 + r] -= __expf(sv - FIXM);          // exact cancel
            posArr[row_w + s * 16 + lq * 4 + r] = az[r] * 2.0f;  // t forced to 0.5
          }
        }
      }
      if (ct == dct0 + s) {        // diagonal tile for set s
#pragma unroll
        for (int r = 0; r < 4; ++r) {
          if (ln == lq * 4 + r) {
            float tv = fmaxf(ac[r], TEMPV);
            float sv = az[r] * __builtin_amdgcn_rcpf(tv);
            l_[s * 4 + r] -= __expf(sv - FIXM);          // exact cancel
          }
        }
      }
    }
  }

  // reduce across the 16 column-lanes (plain sum; M is fixed), write partial
#pragma unroll
  for (int s = 0; s < 2; ++s) {
#pragma unroll
    for (int r = 0; r < 4; ++r) {
      float ll = l_[s * 4 + r];
#pragma unroll
      for (int off = 1; off < 16; off <<= 1) ll += __shfl_xor(ll, off);
      if (ln == 0)
        sum_part[(size_t)cs * NTOT + row_w + s * 16 + lq * 4 + r] = ll;
    }
  }
}

// ---------------- finalize stage 1: 32 blocks x 256 rows -> partial sums ----------------
__global__ void finalize1_kernel(const float* __restrict__ sum_part,
                                 const float* __restrict__ posArr,
                                 float* __restrict__ partial) {
  const int row = blockIdx.x * 256 + threadIdx.x;
  float sum = 0.0f;
#pragma unroll
  for (int s = 0; s < CS; ++s) sum += sum_part[(size_t)s * NTOT + row];
  float lneg = FIXM + __logf(sum);          // lse over negatives
  float pos  = posArr[row];
  float hi = fmaxf(lneg, pos), lo = fminf(lneg, pos);
  float lse = hi + __logf(1.0f + __expf(lo - hi));   // merge pos into lse
  float v = lse - pos;

#pragma unroll
  for (int off = 32; off > 0; off >>= 1) v += __shfl_xor(v, off);
  __shared__ float red[4];
  const int w = threadIdx.x >> 6;
  if ((threadIdx.x & 63) == 0) red[w] = v;
  __syncthreads();
  if (threadIdx.x == 0) partial[blockIdx.x] = red[0] + red[1] + red[2] + red[3];
}

// ---------------- finalize stage 2: merge 32 partials ----------------
__global__ void finalize2_kernel(const float* __restrict__ partial, float* __restrict__ out) {
  float v = (threadIdx.x < 32) ? partial[threadIdx.x] : 0.0f;
#pragma unroll
  for (int off = 32; off > 0; off >>= 1) v += __shfl_xor(v, off);
  if (threadIdx.x == 0) out[0] = v * (1.0f / NTOT);
}

extern "C" void kernel_launch(void* const* d_in, const int* in_sizes, int n_in,
                              void* d_out, int out_size, void* d_ws, size_t ws_size,
                              hipStream_t stream) {
  const float* z_i = (const float*)d_in[0];
  const float* z_j = (const float*)d_in[1];
  const float* c_i = (const float*)d_in[2];
  const float* c_j = (const float*)d_in[3];

  u16* zbT = (u16*)d_ws;                               // 8 MB tiled bf16 z
  u16* cbT = zbT + (size_t)NTOT * DZ;                  // 2 MB tiled bf16 c
  float* sum_part = (float*)(cbT + (size_t)NTOT * DC); // 8*8192 f32 = 256 KB
  float* posArr   = sum_part + (size_t)CS * NTOT;      // 8192 f32
  float* partial  = posArr + NTOT;                     // 32 f32

  convert_kernel<<<2560, 256, 0, stream>>>(z_i, z_j, c_i, c_j, zbT, cbT);
  fused_kernel<<<512, 256, 0, stream>>>(zbT, cbT, sum_part, posArr);
  finalize1_kernel<<<32, 256, 0, stream>>>(sum_part, posArr, partial);
  finalize2_kernel<<<1, 64, 0, stream>>>(partial, (float*)d_out);
}

// Round 5
// 178.028 us; speedup vs baseline: 1.3448x; 1.3448x over previous
//
#include <hip/hip_runtime.h>
#include <stdint.h>

#define NTOT 8192
#define BHALF 4096
#define DZ 512
#define DC 128
#define CS 8
#define TEMPV 0.5f
#define FIXM 16.0f

typedef __attribute__((ext_vector_type(8))) short short8;     // 8 bf16 (4 VGPRs)
typedef __attribute__((ext_vector_type(8))) unsigned short u16x8;
typedef __attribute__((ext_vector_type(4))) float f32x4;
typedef __attribute__((ext_vector_type(4))) float floatx4;
typedef unsigned short u16;

__device__ __forceinline__ u16 f2bf(float x) {
  uint32_t u = __builtin_bit_cast(uint32_t, x);
  u += 0x7fffu + ((u >> 16) & 1u);   // RNE
  return (u16)(u >> 16);
}

#define MFMA16(a, b, c) __builtin_amdgcn_mfma_f32_16x16x32_bf16((a), (b), (c), 0, 0, 0)

// ---------------- convert: fp32 -> bf16 in MFMA-frag-tiled layout ----------------
// 16B chunk index ((ct*KCH + kk)*64 + lane), lane=(lq,ln), holds
// x[ct*16+ln][kk*32+lq*8 .. +7]: simultaneously the A-frag layout (row-tile ct)
// and the B-frag layout (col-tile ct). All loads coalesced dwordx4.
__global__ void convert_kernel(const float* __restrict__ z_i, const float* __restrict__ z_j,
                               const float* __restrict__ c_i, const float* __restrict__ c_j,
                               u16* __restrict__ zbT, u16* __restrict__ cbT) {
  const int ZCH = NTOT * DZ / 8;   // 524288 16B chunks
  const int CCH = NTOT * DC / 8;   // 131072
  int i = blockIdx.x * blockDim.x + threadIdx.x;
  if (i >= ZCH + CCH) return;
  if (i < ZCH) {
    int lane6 = i & 63;
    int f = i >> 6;                 // ct*16 + kk
    int ct = f >> 4, kk = f & 15;
    int ln = lane6 & 15, lq = lane6 >> 4;
    int row = ct * 16 + ln;
    int k = kk * 32 + lq * 8;
    const float* src = (row < BHALF) ? (z_i + (size_t)row * DZ + k)
                                     : (z_j + (size_t)(row - BHALF) * DZ + k);
    floatx4 v0 = *(const floatx4*)src;
    floatx4 v1 = *(const floatx4*)(src + 4);
    u16x8 o;
    o[0]=f2bf(v0[0]); o[1]=f2bf(v0[1]); o[2]=f2bf(v0[2]); o[3]=f2bf(v0[3]);
    o[4]=f2bf(v1[0]); o[5]=f2bf(v1[1]); o[6]=f2bf(v1[2]); o[7]=f2bf(v1[3]);
    *(u16x8*)(zbT + (size_t)i * 8) = o;
  } else {
    int i2 = i - ZCH;
    int lane6 = i2 & 63;
    int f = i2 >> 6;                // ct*4 + kk
    int ct = f >> 2, kk = f & 3;
    int ln = lane6 & 15, lq = lane6 >> 4;
    int row = ct * 16 + ln;
    int k = kk * 32 + lq * 8;
    const float* src = (row < BHALF) ? (c_i + (size_t)row * DC + k)
                                     : (c_j + (size_t)(row - BHALF) * DC + k);
    floatx4 v0 = *(const floatx4*)src;
    floatx4 v1 = *(const floatx4*)(src + 4);
    u16x8 o;
    o[0]=f2bf(v0[0]); o[1]=f2bf(v0[1]); o[2]=f2bf(v0[2]); o[3]=f2bf(v0[3]);
    o[4]=f2bf(v1[0]); o[5]=f2bf(v1[1]); o[6]=f2bf(v1[2]); o[7]=f2bf(v1[3]);
    *(u16x8*)(cbT + (size_t)i2 * 8) = o;
  }
}

// Stage col-tile ct into LDS buffers (async; frag j is 64 lane-ordered chunks,
// so global src and LDS dst are both contiguous -> global_load_lds dwordx4).
__device__ __forceinline__ void stage_tile(const u16* __restrict__ zbT,
                                           const u16* __restrict__ cbT,
                                           u16* zS, u16* cS,
                                           int ct, int w, int lane) {
#pragma unroll
  for (int c4 = 0; c4 < 4; ++c4) {
    const int j = c4 * 4 + w;
    const u16* src = zbT + ((size_t)(ct * 16 + j) * 64 + lane) * 8;
    __builtin_amdgcn_global_load_lds((const __attribute__((address_space(1))) void*)src,
                                     (__attribute__((address_space(3))) void*)(zS + j * 512),
                                     16, 0, 0);
  }
  const u16* srcc = cbT + ((size_t)(ct * 4 + w) * 64 + lane) * 8;
  __builtin_amdgcn_global_load_lds((const __attribute__((address_space(1))) void*)srcc,
                                   (__attribute__((address_space(3))) void*)(cS + w * 512),
                                   16, 0, 0);
}

// ---------------- fused flash-style lse kernel ----------------
// Block = 4 waves x 32 rows = 128 rows; cs = blk&7 -> one 64-col-tile stripe per
// XCD. Double-buffered LDS staging, ONE barrier per iteration; prefetch for
// tile it+1 is issued right after the barrier that ends tile it-1, so the
// compiler's vmcnt(0)-before-s_barrier drain waits on a load that has had the
// whole compute phase in flight. Buffer invariant: readers of buf^1 finished
// at the previous barrier.
// Fixed-M softmax: l += exp(s-16); pair/diag excluded via wave-uniform
// corrections (exact cancellation); pos merged at finalize.
__launch_bounds__(256, 2)
__global__ void fused_kernel(const u16* __restrict__ zbT, const u16* __restrict__ cbT,
                             float* __restrict__ sum_part, float* __restrict__ posArr) {
  __shared__ __align__(16) u16 zS[2][16 * 512];   // 2 x 16 KB
  __shared__ __align__(16) u16 cS[2][4 * 512];    // 2 x 4 KB

  const int tid  = threadIdx.x;
  const int w    = tid >> 6;
  const int lane = tid & 63;
  const int lq   = lane >> 4;
  const int ln   = lane & 15;

  const int cs = blockIdx.x & 7;
  const int rb = blockIdx.x >> 3;
  const int row_w = rb * 128 + w * 32;      // wave's 32 rows (2 sets of 16)
  const int rt0   = row_w >> 4;

  // A fragments (coalesced from tiled layout; chunk stride 64*8 u16 = 512)
  short8 a_z0[16], a_z1[16], a_c0[4], a_c1[4];
  {
    const u16* p0 = zbT + ((size_t)(rt0 * 16) * 64 + lane) * 8;
    const u16* p1 = zbT + ((size_t)((rt0 + 1) * 16) * 64 + lane) * 8;
#pragma unroll
    for (int kk = 0; kk < 16; ++kk) {
      a_z0[kk] = *(const short8*)(p0 + kk * 512);
      a_z1[kk] = *(const short8*)(p1 + kk * 512);
    }
    const u16* q0 = cbT + ((size_t)(rt0 * 4) * 64 + lane) * 8;
    const u16* q1 = cbT + ((size_t)((rt0 + 1) * 4) * 64 + lane) * 8;
#pragma unroll
    for (int kk = 0; kk < 4; ++kk) {
      a_c0[kk] = *(const short8*)(q0 + kk * 512);
      a_c1[kk] = *(const short8*)(q1 + kk * 512);
    }
  }

  float l_[8];
#pragma unroll
  for (int r = 0; r < 8; ++r) l_[r] = 0.0f;

  const int pct0 = (row_w ^ BHALF) >> 4;   // pair col-tile for set0 (set1: +1)
  const int dct0 = rt0;                    // diag col-tile for set0 (set1: +1)
  const int ct_base = cs * 64;

  stage_tile(zbT, cbT, zS[0], cS[0], ct_base, w, lane);
  __syncthreads();   // drains the initial stage

  for (int it = 0; it < 64; ++it) {
    const int ct  = ct_base + it;
    const int cur = it & 1;

    if (it + 1 < 64)
      stage_tile(zbT, cbT, zS[cur ^ 1], cS[cur ^ 1], ct + 1, w, lane);

    const u16* zb = zS[cur];
    const u16* cb = cS[cur];

    f32x4 ac0 = {0.f,0.f,0.f,0.f}, ac1 = {0.f,0.f,0.f,0.f};
#pragma unroll
    for (int kk = 0; kk < 4; ++kk) {
      const short8 b = *(const short8*)(cb + kk * 512 + lane * 8);
      ac0 = MFMA16(a_c0[kk], b, ac0);
      ac1 = MFMA16(a_c1[kk], b, ac1);
    }
    f32x4 az0 = {0.f,0.f,0.f,0.f}, az1 = {0.f,0.f,0.f,0.f};
#pragma unroll
    for (int kk = 0; kk < 16; ++kk) {
      const short8 b = *(const short8*)(zb + kk * 512 + lane * 8);
      az0 = MFMA16(a_z0[kk], b, az0);
      az1 = MFMA16(a_z1[kk], b, az1);
    }

    // generic epilogue: l += exp(s - M), s = zdot / max(cdot, 0.5)
#pragma unroll
    for (int r = 0; r < 4; ++r) {
      float tv0 = fmaxf(ac0[r], TEMPV);
      float sv0 = az0[r] * __builtin_amdgcn_rcpf(tv0);
      l_[r] += __expf(sv0 - FIXM);
      float tv1 = fmaxf(ac1[r], TEMPV);
      float sv1 = az1[r] * __builtin_amdgcn_rcpf(tv1);
      l_[4 + r] += __expf(sv1 - FIXM);
    }

    // corrections (wave-uniform branches; hit 2+2 of the 64 iterations)
#pragma unroll
    for (int s = 0; s < 2; ++s) {
      const f32x4 az = s ? az1 : az0;
      const f32x4 ac = s ? ac1 : ac0;
      if (ct == pct0 + s) {        // pair column tile for set s
#pragma unroll
        for (int r = 0; r < 4; ++r) {
          if (ln == lq * 4 + r) {  // the pair lane for this row
            float tv = fmaxf(ac[r], TEMPV);
            float sv = az[r] * __builtin_amdgcn_rcpf(tv);
            l_[s * 4 + r] -= __expf(sv - FIXM);          // exact cancel
            posArr[row_w + s * 16 + lq * 4 + r] = az[r] * 2.0f;  // t forced to 0.5
          }
        }
      }
      if (ct == dct0 + s) {        // diagonal tile for set s
#pragma unroll
        for (int r = 0; r < 4; ++r) {
          if (ln == lq * 4 + r) {
            float tv = fmaxf(ac[r], TEMPV);
            float sv = az[r] * __builtin_amdgcn_rcpf(tv);
            l_[s * 4 + r] -= __expf(sv - FIXM);          // exact cancel
          }
        }
      }
    }

    __syncthreads();   // one barrier/iter: drains prefetch, protects cur buffer
  }

  // reduce across the 16 column-lanes (plain sum; M fixed), write partial
#pragma unroll
  for (int s = 0; s < 2; ++s) {
#pragma unroll
    for (int r = 0; r < 4; ++r) {
      float ll = l_[s * 4 + r];
#pragma unroll
      for (int off = 1; off < 16; off <<= 1) ll += __shfl_xor(ll, off);
      if (ln == 0)
        sum_part[(size_t)cs * NTOT + row_w + s * 16 + lq * 4 + r] = ll;
    }
  }
}

// ---------------- finalize stage 1: 32 blocks x 256 rows -> partial sums ----------------
__global__ void finalize1_kernel(const float* __restrict__ sum_part,
                                 const float* __restrict__ posArr,
                                 float* __restrict__ partial) {
  const int row = blockIdx.x * 256 + threadIdx.x;
  float sum = 0.0f;
#pragma unroll
  for (int s = 0; s < CS; ++s) sum += sum_part[(size_t)s * NTOT + row];
  float lneg = FIXM + __logf(sum);          // lse over negatives
  float pos  = posArr[row];
  float hi = fmaxf(lneg, pos), lo = fminf(lneg, pos);
  float lse = hi + __logf(1.0f + __expf(lo - hi));   // merge pos into lse
  float v = lse - pos;

#pragma unroll
  for (int off = 32; off > 0; off >>= 1) v += __shfl_xor(v, off);
  __shared__ float red[4];
  const int w = threadIdx.x >> 6;
  if ((threadIdx.x & 63) == 0) red[w] = v;
  __syncthreads();
  if (threadIdx.x == 0) partial[blockIdx.x] = red[0] + red[1] + red[2] + red[3];
}

// ---------------- finalize stage 2: merge 32 partials ----------------
__global__ void finalize2_kernel(const float* __restrict__ partial, float* __restrict__ out) {
  float v = (threadIdx.x < 32) ? partial[threadIdx.x] : 0.0f;
#pragma unroll
  for (int off = 32; off > 0; off >>= 1) v += __shfl_xor(v, off);
  if (threadIdx.x == 0) out[0] = v * (1.0f / NTOT);
}

extern "C" void kernel_launch(void* const* d_in, const int* in_sizes, int n_in,
                              void* d_out, int out_size, void* d_ws, size_t ws_size,
                              hipStream_t stream) {
  const float* z_i = (const float*)d_in[0];
  const float* z_j = (const float*)d_in[1];
  const float* c_i = (const float*)d_in[2];
  const float* c_j = (const float*)d_in[3];

  u16* zbT = (u16*)d_ws;                               // 8 MB tiled bf16 z
  u16* cbT = zbT + (size_t)NTOT * DZ;                  // 2 MB tiled bf16 c
  float* sum_part = (float*)(cbT + (size_t)NTOT * DC); // 8*8192 f32
  float* posArr   = sum_part + (size_t)CS * NTOT;      // 8192 f32
  float* partial  = posArr + NTOT;                     // 32 f32

  convert_kernel<<<2560, 256, 0, stream>>>(z_i, z_j, c_i, c_j, zbT, cbT);
  fused_kernel<<<512, 256, 0, stream>>>(zbT, cbT, sum_part, posArr);
  finalize1_kernel<<<32, 256, 0, stream>>>(sum_part, posArr, partial);
  finalize2_kernel<<<1, 64, 0, stream>>>(partial, (float*)d_out);
}

// Round 6
// 146.658 us; speedup vs baseline: 1.6325x; 1.2139x over previous
//
#include <hip/hip_runtime.h>
#include <stdint.h>

#define NTOT 8192
#define BHALF 4096
#define DZ 512
#define DC 128
#define CS 16
#define TILES_PER_STRIPE 32     // 512 cols / 16
#define TEMPV 0.5f
#define FIXM 16.0f

typedef __attribute__((ext_vector_type(4))) float f32x4;
typedef __attribute__((ext_vector_type(4))) float floatx4;
typedef __attribute__((ext_vector_type(2))) unsigned long ulong2v;  // 16B = 2 fp8 frags
typedef __attribute__((ext_vector_type(4))) unsigned int uint4v;

#define MFMA8(a, b, c) __builtin_amdgcn_mfma_f32_16x16x32_fp8_fp8((long)(a), (long)(b), (c), 0, 0, 0)

// pack 4 floats -> 4 e4m3 bytes in one u32 (HW cvt, saturating)
__device__ __forceinline__ uint32_t pk4_e4m3(float f0, float f1, float f2, float f3) {
  int w = 0;
  w = __builtin_amdgcn_cvt_pk_fp8_f32(f0, f1, w, false);
  w = __builtin_amdgcn_cvt_pk_fp8_f32(f2, f3, w, true);
  return (uint32_t)w;
}

// ---------------- convert: fp32 -> fp8 e4m3, MFMA-frag-pair-tiled layout ----------------
// 16B chunk index ((ct*KP + cc)*64 + lane), lane=(lq,ln): bytes 0..7 = frag 2cc
//   = x[ct*16+ln][cc*64 + lq*8 .. +8), bytes 8..15 = frag 2cc+1 (k +32).
// Simultaneously the A-frag layout (row-tile ct) and B-frag layout (col-tile ct);
// one 16B load = two fp8 MFMA operands. KP: z=8, c=2.
__global__ void convert_kernel(const float* __restrict__ z_i, const float* __restrict__ z_j,
                               const float* __restrict__ c_i, const float* __restrict__ c_j,
                               uint8_t* __restrict__ zbT, uint8_t* __restrict__ cbT) {
  const int ZC = NTOT * DZ / 16;   // 262144 chunks
  const int CC = NTOT * DC / 16;   // 65536
  int i = blockIdx.x * blockDim.x + threadIdx.x;
  if (i >= ZC + CC) return;
  const float* src;
  uint8_t* dst;
  int k0;
  if (i < ZC) {
    int lane = i & 63, g = i >> 6;
    int ct = g >> 3, cc = g & 7;
    int ln = lane & 15, lq = lane >> 4;
    int row = ct * 16 + ln;
    k0 = cc * 64 + lq * 8;
    src = (row < BHALF) ? (z_i + (size_t)row * DZ) : (z_j + (size_t)(row - BHALF) * DZ);
    dst = zbT + (size_t)i * 16;
  } else {
    int i2 = i - ZC;
    int lane = i2 & 63, g = i2 >> 6;
    int ct = g >> 1, cc = g & 1;
    int ln = lane & 15, lq = lane >> 4;
    int row = ct * 16 + ln;
    k0 = cc * 64 + lq * 8;
    src = (row < BHALF) ? (c_i + (size_t)row * DC) : (c_j + (size_t)(row - BHALF) * DC);
    dst = cbT + (size_t)i2 * 16;
  }
  floatx4 a0 = *(const floatx4*)(src + k0);
  floatx4 a1 = *(const floatx4*)(src + k0 + 4);
  floatx4 b0 = *(const floatx4*)(src + k0 + 32);
  floatx4 b1 = *(const floatx4*)(src + k0 + 36);
  uint4v o;
  o.x = pk4_e4m3(a0[0], a0[1], a0[2], a0[3]);
  o.y = pk4_e4m3(a1[0], a1[1], a1[2], a1[3]);
  o.z = pk4_e4m3(b0[0], b0[1], b0[2], b0[3]);
  o.w = pk4_e4m3(b1[0], b1[1], b1[2], b1[3]);
  *(uint4v*)dst = o;
}

// stage col-tile ct into LDS (async, lane-ordered, 16B)
__device__ __forceinline__ void stage_tile(const uint8_t* __restrict__ zbT,
                                           const uint8_t* __restrict__ cbT,
                                           uint8_t* zS, uint8_t* cS,
                                           int ct, int w, int lane) {
#pragma unroll
  for (int j = 0; j < 2; ++j) {
    const int cc = w * 2 + j;
    const uint8_t* src = zbT + (((size_t)ct * 8 + cc) * 64 + lane) * 16;
    __builtin_amdgcn_global_load_lds((const __attribute__((address_space(1))) void*)src,
                                     (__attribute__((address_space(3))) void*)(zS + cc * 1024),
                                     16, 0, 0);
  }
  if (w < 2) {
    const uint8_t* src = cbT + (((size_t)ct * 2 + w) * 64 + lane) * 16;
    __builtin_amdgcn_global_load_lds((const __attribute__((address_space(1))) void*)src,
                                     (__attribute__((address_space(3))) void*)(cS + w * 1024),
                                     16, 0, 0);
  }
}

// ---------------- fused flash-style lse kernel (fp8, no online max) ----------------
// Block = 4 waves x 32 rows = 128 rows; stripe cs = blk&15 -> 512 cols, 32 tiles.
// Double-buffered LDS, one barrier/iter, prefetch issued right after barrier.
// Fixed-M: l += exp(s-16); pair/diag excluded via wave-uniform exact-cancel
// corrections (same registers). pos is NOT computed here (exact fp32 at finalize).
__launch_bounds__(256, 4)
__global__ void fused_kernel(const uint8_t* __restrict__ zbT, const uint8_t* __restrict__ cbT,
                             float* __restrict__ sum_part) {
  __shared__ __align__(16) uint8_t zS[2][8192];   // 2 x 8 KB
  __shared__ __align__(16) uint8_t cS[2][2048];   // 2 x 2 KB

  const int tid  = threadIdx.x;
  const int w    = tid >> 6;
  const int lane = tid & 63;
  const int lq   = lane >> 4;
  const int ln   = lane & 15;

  const int cs = blockIdx.x & 15;
  const int rb = blockIdx.x >> 4;
  const int row_w = rb * 128 + w * 32;      // wave's 32 rows (2 sets of 16)
  const int rt0   = row_w >> 4;

  // A fragment pairs (each ulong2v = frags 2c, 2c+1)
  ulong2v a_z0[8], a_z1[8], a_c0[2], a_c1[2];
  {
    const uint8_t* p0 = zbT + ((size_t)rt0 * 8 * 64 + lane) * 16;
    const uint8_t* p1 = zbT + ((size_t)(rt0 + 1) * 8 * 64 + lane) * 16;
#pragma unroll
    for (int c = 0; c < 8; ++c) {
      a_z0[c] = *(const ulong2v*)(p0 + (size_t)c * 1024);
      a_z1[c] = *(const ulong2v*)(p1 + (size_t)c * 1024);
    }
    const uint8_t* q0 = cbT + ((size_t)rt0 * 2 * 64 + lane) * 16;
    const uint8_t* q1 = cbT + ((size_t)(rt0 + 1) * 2 * 64 + lane) * 16;
#pragma unroll
    for (int c = 0; c < 2; ++c) {
      a_c0[c] = *(const ulong2v*)(q0 + (size_t)c * 1024);
      a_c1[c] = *(const ulong2v*)(q1 + (size_t)c * 1024);
    }
  }

  float l_[8];
#pragma unroll
  for (int r = 0; r < 8; ++r) l_[r] = 0.0f;

  const int pct0 = (row_w ^ BHALF) >> 4;   // pair col-tile (set0; set1 = +1)
  const int dct0 = rt0;                    // diag col-tile (set0; set1 = +1)
  const int ct_base = cs * TILES_PER_STRIPE;

  stage_tile(zbT, cbT, zS[0], cS[0], ct_base, w, lane);
  __syncthreads();

  for (int it = 0; it < TILES_PER_STRIPE; ++it) {
    const int ct  = ct_base + it;
    const int cur = it & 1;

    if (it + 1 < TILES_PER_STRIPE)
      stage_tile(zbT, cbT, zS[cur ^ 1], cS[cur ^ 1], ct + 1, w, lane);

    const uint8_t* zb = zS[cur];
    const uint8_t* cb = cS[cur];

    f32x4 ac0 = {0.f,0.f,0.f,0.f}, ac1 = {0.f,0.f,0.f,0.f};
#pragma unroll
    for (int c = 0; c < 2; ++c) {
      const ulong2v b = *(const ulong2v*)(cb + c * 1024 + lane * 16);
      ac0 = MFMA8(a_c0[c].x, b.x, ac0);
      ac0 = MFMA8(a_c0[c].y, b.y, ac0);
      ac1 = MFMA8(a_c1[c].x, b.x, ac1);
      ac1 = MFMA8(a_c1[c].y, b.y, ac1);
    }
    f32x4 az0 = {0.f,0.f,0.f,0.f}, az1 = {0.f,0.f,0.f,0.f};
#pragma unroll
    for (int c = 0; c < 8; ++c) {
      const ulong2v b = *(const ulong2v*)(zb + c * 1024 + lane * 16);
      az0 = MFMA8(a_z0[c].x, b.x, az0);
      az0 = MFMA8(a_z0[c].y, b.y, az0);
      az1 = MFMA8(a_z1[c].x, b.x, az1);
      az1 = MFMA8(a_z1[c].y, b.y, az1);
    }

    // generic epilogue: l += exp(s - M), s = zdot / max(cdot, 0.5)
#pragma unroll
    for (int r = 0; r < 4; ++r) {
      float tv0 = fmaxf(ac0[r], TEMPV);
      float sv0 = az0[r] * __builtin_amdgcn_rcpf(tv0);
      l_[r] += __expf(sv0 - FIXM);
      float tv1 = fmaxf(ac1[r], TEMPV);
      float sv1 = az1[r] * __builtin_amdgcn_rcpf(tv1);
      l_[4 + r] += __expf(sv1 - FIXM);
    }

    // wave-uniform corrections: exact cancel of pair/diag (same register values)
#pragma unroll
    for (int s = 0; s < 2; ++s) {
      const f32x4 az = s ? az1 : az0;
      const f32x4 ac = s ? ac1 : ac0;
      if (ct == pct0 + s) {
#pragma unroll
        for (int r = 0; r < 4; ++r) {
          if (ln == lq * 4 + r) {
            float tv = fmaxf(ac[r], TEMPV);
            float sv = az[r] * __builtin_amdgcn_rcpf(tv);
            l_[s * 4 + r] -= __expf(sv - FIXM);
          }
        }
      }
      if (ct == dct0 + s) {
#pragma unroll
        for (int r = 0; r < 4; ++r) {
          if (ln == lq * 4 + r) {
            float tv = fmaxf(ac[r], TEMPV);
            float sv = az[r] * __builtin_amdgcn_rcpf(tv);
            l_[s * 4 + r] -= __expf(sv - FIXM);
          }
        }
      }
    }

    __syncthreads();   // one barrier/iter: drains prefetch, protects cur buffer
  }

  // reduce across the 16 column-lanes, write per-stripe partial sums
#pragma unroll
  for (int s = 0; s < 2; ++s) {
#pragma unroll
    for (int r = 0; r < 4; ++r) {
      float ll = l_[s * 4 + r];
#pragma unroll
      for (int off = 1; off < 16; off <<= 1) ll += __shfl_xor(ll, off);
      if (ln == 0)
        sum_part[(size_t)cs * NTOT + row_w + s * 16 + lq * 4 + r] = ll;
    }
  }
}

// ---------------- finalize: exact fp32 pos + stripe merge + reduction ----------------
// 512 blocks x 1024 thr (16 waves); one wave per row.
__global__ void finalize_kernel(const float* __restrict__ z_i, const float* __restrict__ z_j,
                                const float* __restrict__ sum_part,
                                float* __restrict__ out) {
  const int tid  = threadIdx.x;
  const int w    = tid >> 6;
  const int lane = tid & 63;
  const int row  = blockIdx.x * 16 + w;

  // exact pos: fp32 dot(z[row], z[row^B]) * 2
  const float* zr = (row < BHALF) ? (z_i + (size_t)row * DZ) : (z_j + (size_t)(row - BHALF) * DZ);
  const float* zp = (row < BHALF) ? (z_j + (size_t)row * DZ) : (z_i + (size_t)(row - BHALF) * DZ);
  const int o = lane * 8;
  floatx4 a0 = *(const floatx4*)(zr + o), a1 = *(const floatx4*)(zr + o + 4);
  floatx4 b0 = *(const floatx4*)(zp + o), b1 = *(const floatx4*)(zp + o + 4);
  float d = a0[0]*b0[0] + a0[1]*b0[1] + a0[2]*b0[2] + a0[3]*b0[3]
          + a1[0]*b1[0] + a1[1]*b1[1] + a1[2]*b1[2] + a1[3]*b1[3];
#pragma unroll
  for (int off = 1; off < 64; off <<= 1) d += __shfl_xor(d, off);

  float ns = (lane < CS) ? sum_part[(size_t)lane * NTOT + row] : 0.0f;
#pragma unroll
  for (int off = 1; off < 64; off <<= 1) ns += __shfl_xor(ns, off);

  __shared__ float red[16];
  if (lane == 0) {
    float pos  = 2.0f * d;
    float lneg = FIXM + __logf(ns);
    float hi = fmaxf(lneg, pos), lo = fminf(lneg, pos);
    float lse = hi + __logf(1.0f + __expf(lo - hi));
    red[w] = lse - pos;
  }
  __syncthreads();
  if (tid == 0) {
    float s = 0.0f;
#pragma unroll
    for (int i = 0; i < 16; ++i) s += red[i];
    atomicAdd(out, s * (1.0f / NTOT));
  }
}

extern "C" void kernel_launch(void* const* d_in, const int* in_sizes, int n_in,
                              void* d_out, int out_size, void* d_ws, size_t ws_size,
                              hipStream_t stream) {
  const float* z_i = (const float*)d_in[0];
  const float* z_j = (const float*)d_in[1];
  const float* c_i = (const float*)d_in[2];
  const float* c_j = (const float*)d_in[3];

  uint8_t* zbT = (uint8_t*)d_ws;                        // 4 MB fp8 z (tiled)
  uint8_t* cbT = zbT + (size_t)NTOT * DZ;               // 1 MB fp8 c (tiled)
  float* sum_part = (float*)(cbT + (size_t)NTOT * DC);  // 16*8192 f32 = 512 KB

  hipMemsetAsync(d_out, 0, sizeof(float), stream);      // atomic target
  convert_kernel<<<1280, 256, 0, stream>>>(z_i, z_j, c_i, c_j, zbT, cbT);
  fused_kernel<<<1024, 256, 0, stream>>>(zbT, cbT, sum_part);
  finalize_kernel<<<512, 1024, 0, stream>>>(z_i, z_j, sum_part, (float*)d_out);
}